// Round 8
// baseline (518.281 us; speedup 1.0000x reference)
//
#include <hip/hip_runtime.h>
#include <math.h>

#define B_DIM 128
#define T_DIM 50
#define LEAF  4880
#define A_DIM 64
#define ATTN  128
#define RNN   128
#define NC    283
#define M_TOT (B_DIM*T_DIM)   // 6400
#define KSPLIT 5
#define NCH 153               // ceil(4880/32); chunk 152 has 16 valid k
#define WT_PLANE (NCH*512*8)  // 626688 ushort per plane (hi / lo)

using short8 = __attribute__((ext_vector_type(8))) short;
using f32x4  = __attribute__((ext_vector_type(4))) float;

__device__ __forceinline__ float sigmoidf_(float x) {
  return 1.0f / (1.0f + __expf(-x));
}

// RNE fp32 -> bf16 bits (used in one-time W prep)
__device__ __forceinline__ unsigned short f32_to_bf16_rne(float f) {
  unsigned int u = __float_as_uint(f);
  unsigned int r = u + 0x7FFFu + ((u >> 16) & 1u);
  return (unsigned short)(r >> 16);
}
__device__ __forceinline__ float bf16_bits_to_f32(unsigned short b) {
  return __uint_as_float(((unsigned int)b) << 16);
}

// ---------------------------------------------------------------------------
// Pre-transpose W[4880,128] into MFMA B-fragment order, hi/lo bf16 planes.
// Wt[plane][c][nt][lane][j]: lane holds W[k=c*32+(lane>>4)*8+j][nt*16+(lane&15)]
// ---------------------------------------------------------------------------
__global__ __launch_bounds__(256) void k_prep_wt(
    const float* __restrict__ Wd, unsigned short* __restrict__ Wt) {
  const int u = blockIdx.x * 256 + threadIdx.x;   // 0 .. 78335 (NCH*512)
  const int c = u >> 9, rem = u & 511;
  const int nt = rem >> 6, lane = rem & 63;
  const int n = nt * 16 + (lane & 15);
  const int kb = c * 32 + ((lane >> 4) << 3);
  short8 h8, l8;
  #pragma unroll
  for (int j = 0; j < 8; ++j) {
    int k = kb + j;
    float v = (k < LEAF) ? Wd[(size_t)k * 128 + n] : 0.0f;
    unsigned short hb = f32_to_bf16_rne(v);
    unsigned short lb = f32_to_bf16_rne(v - bf16_bits_to_f32(hb));
    h8[j] = (short)hb;
    l8[j] = (short)lb;
  }
  *(short8*)&Wt[(size_t)u * 8] = h8;
  *(short8*)&Wt[(size_t)WT_PLANE + (size_t)u * 8] = l8;
}

// ---------------------------------------------------------------------------
// Big GEMM via MFMA, v3: NO LDS, NO barriers.
// R7 was LDS-staging/barrier-bound (LDS ~450 cyc/chunk vs MFMA ~116, 2 barriers
// draining vmcnt, 2.9M bank-conflict cycles on A-frag writes; MfmaUtil 11.5%).
// v3 loads BOTH operands directly into fragment layout from global:
//  - B: Wt is pre-stored in fragment order -> lane-linear 16B loads (L2-hot).
//  - A: frag is A[m=lane&15][k=(lane>>4)*8+j] -> lane's 8 k are CONTIGUOUS fp32
//       in A -> two float4 loads, converted in-register to hi/lo bf16.
// Trunc-split (hi=top16, lo=bf16(v-hi)) reconstructs v to 2^-17 — safe: absmax
// was bit-identical between pure-fp32 (R1) and RNE-split (R6/R7) runs.
// Each wave owns 32 rows x 64 cols, free-runs its K-range with software
// prefetch: A(c+1) after convert, B(c+1) interleaved 1:1 with MFMA (AITER
// pattern). Grid (100,KSPLIT) = 500 blocks x 4 waves = 2000 independent waves.
// All register arrays indexed by unroll literals only (R4 lesson).
// ---------------------------------------------------------------------------
__global__ __launch_bounds__(256) void k_gemm_mfma(
    const float* __restrict__ Ax, const unsigned short* __restrict__ Wt,
    float* __restrict__ P) {
  const int tid   = threadIdx.x;
  const int lane  = tid & 63;
  const int w     = tid >> 6;
  const int mpair = w >> 1;        // which 32-row group of the block's 64
  const int nh    = w & 1;         // which 64-col half
  const int R0    = blockIdx.x * 64 + mpair * 32;
  const int s     = blockIdx.y;
  const int c0    = (s * NCH) / KSPLIT;
  const int c1    = ((s + 1) * NCH) / KSPLIT;

  const int klane = (lane >> 4) << 3;             // k offset within chunk
  const float* pA0 = Ax + (size_t)(R0 + (lane & 15)) * LEAF + klane;  // msub0
  const float* pA1 = pA0 + (size_t)16 * LEAF;                          // msub1
  const unsigned short* pB = Wt + ((size_t)(nh * 4) * 64 + lane) * 8;

  f32x4 acc[2][4];
  #pragma unroll
  for (int m = 0; m < 2; ++m)
    #pragma unroll
    for (int i = 0; i < 4; ++i)
      #pragma unroll
      for (int q = 0; q < 4; ++q) acc[m][i][q] = 0.0f;

  float4 rA[4];
  short8 rB[8];

  // ---- prologue: load chunk c0 ----
  {
    const int kg = c0 * 32 + klane;
    if (kg + 8 <= LEAF) {
      rA[0] = *(const float4*)(pA0 + (size_t)c0 * 32);
      rA[1] = *(const float4*)(pA0 + (size_t)c0 * 32 + 4);
      rA[2] = *(const float4*)(pA1 + (size_t)c0 * 32);
      rA[3] = *(const float4*)(pA1 + (size_t)c0 * 32 + 4);
    } else {
      rA[0] = rA[1] = rA[2] = rA[3] = make_float4(0.f, 0.f, 0.f, 0.f);
    }
    const unsigned short* bp = pB + (size_t)c0 * 4096;
    #pragma unroll
    for (int i = 0; i < 4; ++i) {
      rB[2 * i]     = *(const short8*)(bp + i * 512);
      rB[2 * i + 1] = *(const short8*)(bp + WT_PLANE + i * 512);
    }
  }

  for (int c = c0; c < c1; ++c) {
    // ---- convert A(c) fp32 -> hi/lo bf16 fragments (registers only) ----
    short8 aHi[2], aLo[2];
    #pragma unroll
    for (int m = 0; m < 2; ++m) {
      float vv[8] = {rA[2*m].x, rA[2*m].y, rA[2*m].z, rA[2*m].w,
                     rA[2*m+1].x, rA[2*m+1].y, rA[2*m+1].z, rA[2*m+1].w};
      #pragma unroll
      for (int j = 0; j < 8; ++j) {
        unsigned int u = __float_as_uint(vv[j]);
        unsigned short hb = (unsigned short)(u >> 16);          // trunc hi
        float lf = vv[j] - __uint_as_float(u & 0xFFFF0000u);    // exact residual
        aHi[m][j] = (short)hb;
        aLo[m][j] = (short)(unsigned short)(__float_as_uint(lf) >> 16);
      }
    }
    // ---- prefetch A(c+1): rA free after convert ----
    if (c + 1 < c1) {
      const int cn = c + 1;
      const int kg = cn * 32 + klane;
      if (kg + 8 <= LEAF) {
        rA[0] = *(const float4*)(pA0 + (size_t)cn * 32);
        rA[1] = *(const float4*)(pA0 + (size_t)cn * 32 + 4);
        rA[2] = *(const float4*)(pA1 + (size_t)cn * 32);
        rA[3] = *(const float4*)(pA1 + (size_t)cn * 32 + 4);
      } else {
        rA[0] = rA[1] = rA[2] = rA[3] = make_float4(0.f, 0.f, 0.f, 0.f);
      }
    }
    // ---- MFMA, with B(c+1) prefetch interleaved 1:1 ----
    #pragma unroll
    for (int i = 0; i < 4; ++i) {
      short8 bh = rB[2 * i];
      short8 bl = rB[2 * i + 1];
      if (c + 1 < c1) {
        const unsigned short* bp = pB + (size_t)(c + 1) * 4096;
        rB[2 * i]     = *(const short8*)(bp + i * 512);
        rB[2 * i + 1] = *(const short8*)(bp + WT_PLANE + i * 512);
      }
      #pragma unroll
      for (int m = 0; m < 2; ++m) {
        acc[m][i] = __builtin_amdgcn_mfma_f32_16x16x32_bf16(aHi[m], bl, acc[m][i], 0, 0, 0);
        acc[m][i] = __builtin_amdgcn_mfma_f32_16x16x32_bf16(aLo[m], bh, acc[m][i], 0, 0, 0);
        acc[m][i] = __builtin_amdgcn_mfma_f32_16x16x32_bf16(aHi[m], bh, acc[m][i], 0, 0, 0);
      }
    }
  }

  // epilogue: C/D layout col=lane&15, row=(lane>>4)*4+r
  float* outp = P + (size_t)s * ((size_t)M_TOT * 128);
  const int rbase = R0 + ((lane >> 4) << 2);
  const int col = nh * 64 + (lane & 15);
  #pragma unroll
  for (int m = 0; m < 2; ++m)
    #pragma unroll
    for (int i = 0; i < 4; ++i)
      #pragma unroll
      for (int r = 0; r < 4; ++r)
        outp[(size_t)(rbase + m * 16 + r) * 128 + col + i * 16] = acc[m][i][r];
}

// ---------------------------------------------------------------------------
// Reduce KSPLIT partials + tanh (X aliases P slot 0; elementwise-safe).
// ---------------------------------------------------------------------------
__global__ __launch_bounds__(256) void k_reduce_tanh(
    float* __restrict__ P, float* __restrict__ X) {
  const size_t i = ((size_t)blockIdx.x * 256 + threadIdx.x) * 4;
  float4 a = *(const float4*)&P[i];
  #pragma unroll
  for (int s = 1; s < KSPLIT; ++s) {
    float4 b = *(const float4*)&P[(size_t)s * (M_TOT * 128) + i];
    a.x += b.x; a.y += b.y; a.z += b.z; a.w += b.w;
  }
  a.x = tanhf(a.x); a.y = tanhf(a.y); a.z = tanhf(a.z); a.w = tanhf(a.w);
  *(float4*)&X[i] = a;
}

// ---------------------------------------------------------------------------
// Generic small GEMM: C[M,N] = A[M,K] @ Bw[N,K]^T + bias  (opt sigmoid*mask)
// ---------------------------------------------------------------------------
template<int K, int ACT>
__global__ __launch_bounds__(256) void k_gemm_bn(
    const float* __restrict__ A, const float* __restrict__ Bw,
    const float* __restrict__ bias, const float* __restrict__ maskv,
    float* __restrict__ C, int N, int ldc) {
  __shared__ __align__(16) float Asm[32][K + 4];
  const int tid = threadIdx.x;
  const int m0 = blockIdx.x * 32;
  const int n0 = blockIdx.y * 64;
  constexpr int K4 = K / 4;

  #pragma unroll
  for (int i = 0; i < (32 * K4) / 256; ++i) {
    int idx = tid + i * 256;
    int row = idx / K4, k4 = idx % K4;
    float4 v = *(const float4*)&A[(size_t)(m0 + row) * K + k4 * 4];
    *(float4*)&Asm[row][k4 * 4] = v;
  }
  __syncthreads();

  const int n2 = tid & 31, mg = tid >> 5;
  const int n = n0 + n2 * 2;
  const int ns0 = min(n, N - 1), ns1 = min(n + 1, N - 1);
  const float* Bp0 = Bw + (size_t)ns0 * K;
  const float* Bp1 = Bw + (size_t)ns1 * K;

  float acc[4][2] = {};
  #pragma unroll 4
  for (int k = 0; k < K; k += 4) {
    float4 b0 = *(const float4*)&Bp0[k];
    float4 b1 = *(const float4*)&Bp1[k];
    #pragma unroll
    for (int r = 0; r < 4; ++r) {
      float4 a = *(const float4*)&Asm[mg * 4 + r][k];
      acc[r][0] += a.x * b0.x + a.y * b0.y + a.z * b0.z + a.w * b0.w;
      acc[r][1] += a.x * b1.x + a.y * b1.y + a.z * b1.z + a.w * b1.w;
    }
  }

  #pragma unroll
  for (int r = 0; r < 4; ++r) {
    int m = m0 + mg * 4 + r;
    #pragma unroll
    for (int c = 0; c < 2; ++c) {
      int nn = n + c;
      if (nn < N) {
        float v = acc[r][c] + bias[nn];
        if (ACT) v = sigmoidf_(v) * maskv[m];
        C[(size_t)m * ldc + nn] = v;
      }
    }
  }
}

// ---------------------------------------------------------------------------
// GRU scan v3 (R5-proven). One block per batch row; 512 threads.
// Weights pre-rotated at load (register arrays use unroll-constant indices
// only). n-gate bias INSIDE r*: n = tanh(xn + r*(Wn.h + bn)).
// ---------------------------------------------------------------------------
__global__ __launch_bounds__(512) void k_gru(
    const float* __restrict__ xW, const float* __restrict__ Whh,
    const float* __restrict__ bhh, float* __restrict__ Hout) {
  const int b = blockIdx.x;
  const int tid = threadIdx.x;
  const int j  = tid >> 2;
  const int qf = tid & 3;
  __shared__ __align__(16) float hs[2][128];

  float4 wr[8], wz[8], wn[8];
  {
    const float* pr = Whh + (size_t)j * 128 + qf * 32;
    const float* pz = Whh + (size_t)(j + 128) * 128 + qf * 32;
    const float* pn = Whh + (size_t)(j + 256) * 128 + qf * 32;
    #pragma unroll
    for (int k = 0; k < 8; ++k) {
      const int c = (k + qf * 2) & 7;   // rotation folded into the LOAD
      wr[k] = *(const float4*)(pr + c * 4);
      wz[k] = *(const float4*)(pz + c * 4);
      wn[k] = *(const float4*)(pn + c * 4);
    }
  }
  const float br = bhh[j], bz = bhh[j + 128], bn_ = bhh[j + 256];

  if (tid < 128) hs[0][tid] = 0.0f;
  const float* xwb = xW + (size_t)b * 50 * 384;
  float xr = 0.f, xz = 0.f, xn = 0.f;
  if (qf == 0) { xr = xwb[j]; xz = xwb[128 + j]; xn = xwb[256 + j]; }
  __syncthreads();

  int cur = 0;
  for (int t = 0; t < 50; ++t) {
    float nxr = 0.f, nxz = 0.f, nxn = 0.f;
    if (qf == 0 && t + 1 < 50) {
      const float* xwn = xwb + (size_t)(t + 1) * 384;
      nxr = xwn[j]; nxz = xwn[128 + j]; nxn = xwn[256 + j];
    }

    float ar = 0.f, az = 0.f, an = 0.f;
    #pragma unroll
    for (int k = 0; k < 8; ++k) {
      const int c = (k + qf * 2) & 7;   // runtime -> LDS address only
      float4 hv = *(const float4*)&hs[cur][qf * 32 + c * 4];
      ar += wr[k].x * hv.x + wr[k].y * hv.y + wr[k].z * hv.z + wr[k].w * hv.w;
      az += wz[k].x * hv.x + wz[k].y * hv.y + wz[k].z * hv.z + wz[k].w * hv.w;
      an += wn[k].x * hv.x + wn[k].y * hv.y + wn[k].z * hv.z + wn[k].w * hv.w;
    }
    ar += __shfl_xor(ar, 1); ar += __shfl_xor(ar, 2);
    az += __shfl_xor(az, 1); az += __shfl_xor(az, 2);
    an += __shfl_xor(an, 1); an += __shfl_xor(an, 2);

    if (qf == 0) {
      float r = sigmoidf_(xr + ar + br);
      float z = sigmoidf_(xz + az + bz);
      float nn = tanhf(xn + r * (an + bn_));   // bias INSIDE r*
      float h = (1.f - z) * nn + z * hs[cur][j];
      hs[cur ^ 1][j] = h;
      Hout[(size_t)(b * 50 + t) * 128 + j] = h;
    }
    __syncthreads();
    cur ^= 1;
    xr = nxr; xz = nxz; xn = nxn;
  }
}

// ---------------------------------------------------------------------------
// Attention: per (b,t) block (6400 blocks, 128 threads).
// ---------------------------------------------------------------------------
__global__ __launch_bounds__(128) void k_attn(
    const float* __restrict__ H2, const int* __restrict__ F,
    const float* __restrict__ emb, float* __restrict__ S) {
  const int m = blockIdx.x;
  const int tid = threadIdx.x;
  __shared__ __align__(16) float outs[128];
  __shared__ __align__(16) float Ls[64][132];
  __shared__ float hls[64];
  __shared__ float wts[64];
  __shared__ int fs[64];

  outs[tid] = H2[(size_t)m * 128 + tid];
  if (tid < 64) fs[tid] = F[(size_t)m * 64 + tid];
  __syncthreads();

  #pragma unroll
  for (int i = 0; i < 16; ++i) {
    int idx = tid + i * 128;
    int a = idx >> 5, c4 = idx & 31;
    float4 v = *(const float4*)&emb[(size_t)fs[a] * 128 + c4 * 4];
    *(float4*)&Ls[a][c4 * 4] = v;
  }
  __syncthreads();

  {
    const int a = tid >> 1, hf = tid & 1;
    float sum = 0.f;
    #pragma unroll
    for (int j = 0; j < 16; ++j) {
      float4 lv = *(const float4*)&Ls[a][hf * 64 + j * 4];
      float4 ov = *(const float4*)&outs[hf * 64 + j * 4];
      sum += lv.x * ov.x + lv.y * ov.y + lv.z * ov.z + lv.w * ov.w;
    }
    float other = __shfl_xor(sum, 1);
    sum += other;
    if (hf == 0) hls[a] = sum + (fs[a] > 0 ? 0.0f : -1e30f);
  }
  __syncthreads();

  if (tid < 64) {
    float v = hls[tid];
    float mx = v;
    #pragma unroll
    for (int o = 32; o; o >>= 1) mx = fmaxf(mx, __shfl_xor(mx, o));
    float e = __expf(v - mx);
    float sm = e;
    #pragma unroll
    for (int o = 32; o; o >>= 1) sm += __shfl_xor(sm, o);
    wts[tid] = e / sm;
  }
  __syncthreads();

  float kv = 0.f;
  #pragma unroll 8
  for (int a2 = 0; a2 < 64; ++a2) kv += wts[a2] * Ls[a2][tid];

  S[(size_t)m * 256 + tid] = outs[tid];
  S[(size_t)m * 256 + 128 + tid] = kv;
}

// ---------------------------------------------------------------------------
extern "C" void kernel_launch(void* const* d_in, const int* in_sizes, int n_in,
                              void* d_out, int out_size, void* d_ws, size_t ws_size,
                              hipStream_t stream) {
  const float* inputs_x  = (const float*)d_in[0];
  const int*   inputs_f  = (const int*)d_in[1];
  const float* mask_seqs = (const float*)d_in[2];
  const float* dag_emb   = (const float*)d_in[3];
  const float* embed_a   = (const float*)d_in[4];
  const float* Wih0 = (const float*)d_in[5];
  const float* Whh0 = (const float*)d_in[6];
  const float* bih0 = (const float*)d_in[7];
  const float* bhh0 = (const float*)d_in[8];
  const float* Wih1 = (const float*)d_in[9];
  const float* Whh1 = (const float*)d_in[10];
  const float* bih1 = (const float*)d_in[11];
  const float* bhh1 = (const float*)d_in[12];
  const float* fc_w = (const float*)d_in[13];
  const float* fc_b = (const float*)d_in[14];
  float* out = (float*)d_out;

  float* ws = (float*)d_ws;
  // Footprint identical to R5-R7 (proven): 5*819200 + 2457600 + 2*819200 floats.
  float* P  = ws;
  float* X  = P;                       // aliases P slot 0 (reduce in-place safe)
  float* S  = P + 819200;              // aliases P slots 1-2 (P dead after reduce)
  float* xW = ws + KSPLIT * 819200;
  float* H1 = xW + 2457600;
  float* H2 = H1 + 819200;
  // Wt (2.5 MB bf16) aliases H1+H2 (6.5 MB): dead before k_gru writes H1.
  unsigned short* Wt = (unsigned short*)H1;

  k_prep_wt<<<306, 256, 0, stream>>>(dag_emb, Wt);
  k_gemm_mfma<<<dim3(100, KSPLIT), 256, 0, stream>>>(inputs_x, Wt, P);
  k_reduce_tanh<<<800, 256, 0, stream>>>(P, X);
  k_gemm_bn<128, 0><<<dim3(200, 6), 256, 0, stream>>>(X, Wih0, bih0, nullptr, xW, 384, 384);
  k_gru<<<128, 512, 0, stream>>>(xW, Whh0, bhh0, H1);
  k_gemm_bn<128, 0><<<dim3(200, 6), 256, 0, stream>>>(H1, Wih1, bih1, nullptr, xW, 384, 384);
  k_gru<<<128, 512, 0, stream>>>(xW, Whh1, bhh1, H2);
  k_attn<<<6400, 128, 0, stream>>>(H2, inputs_f, embed_a, S);
  k_gemm_bn<256, 1><<<dim3(200, 5), 256, 0, stream>>>(S, fc_w, fc_b, mask_seqs, out, 283, 283);
}